// Round 9
// baseline (484.088 us; speedup 1.0000x reference)
//
#include <hip/hip_runtime.h>
#include <hip/hip_bf16.h>
#include <cstdint>

#define DM   1024
#define SEQ  2048
#define NB   4
#define NH   16
// 0.125 * log2(e): folded into W_Q at conversion so exp2(mfma result) is the softmax numerator
#define QSCALE 0.18033688011112042f
#define NEGINF __builtin_bit_cast(float, 0xFF800000u)

typedef __bf16 bf16x8 __attribute__((ext_vector_type(8)));
typedef float  f32x4  __attribute__((ext_vector_type(4)));
typedef unsigned short u16;
typedef u16 u16x4 __attribute__((ext_vector_type(4)));
typedef u16 u16x8 __attribute__((ext_vector_type(8)));
typedef unsigned long long u64;

__device__ __forceinline__ u16 f2bf(float f) {
    uint32_t u = __builtin_bit_cast(uint32_t, f);
    u = (u + 0x7FFFu + ((u >> 16) & 1u)) >> 16;
    return (u16)u;
}
// packed f32 pair -> bf16 pair (RNE), single VALU op
__device__ __forceinline__ uint32_t pk2bf(float lo, float hi) {
    uint32_t r;
    asm("v_cvt_pk_bf16_f32 %0, %1, %2" : "=v"(r) : "v"(lo), "v"(hi));
    return r;
}
__device__ __forceinline__ float ex2(float x) { return __builtin_amdgcn_exp2f(x); }
__device__ __forceinline__ bf16x8 ld_bf8(const u16* p) {
    return __builtin_bit_cast(bf16x8, *reinterpret_cast<const u16x8*>(p));
}

// ---------------- weight convert + transpose: W fp32 [k][n] -> Wt bf16 [n][k] (scaled)
__global__ __launch_bounds__(256) void conv_wt(
    const float* __restrict__ W0, const float* __restrict__ W1,
    const float* __restrict__ W2, const float* __restrict__ W3,
    u16* __restrict__ T0, u16* __restrict__ T1, u16* __restrict__ T2, u16* __restrict__ T3)
{
    const float* W; u16* O; float sc = 1.0f;
    if (blockIdx.z == 0)      { W = W0; O = T0; sc = QSCALE; }
    else if (blockIdx.z == 1) { W = W1; O = T1; }
    else if (blockIdx.z == 2) { W = W2; O = T2; }
    else                      { W = W3; O = T3; }
    __shared__ u16 T[64][72];
    const int t = threadIdx.x;
    const int k0 = blockIdx.x * 64, n0 = blockIdx.y * 64;
    #pragma unroll
    for (int ii = 0; ii < 4; ++ii) {
        int fidx = t + ii * 256;
        int row = fidx >> 4, c4 = fidx & 15;
        float4 v = *reinterpret_cast<const float4*>(W + (size_t)(k0 + row) * DM + n0 + c4 * 4);
        T[c4 * 4 + 0][row] = f2bf(v.x * sc);
        T[c4 * 4 + 1][row] = f2bf(v.y * sc);
        T[c4 * 4 + 2][row] = f2bf(v.z * sc);
        T[c4 * 4 + 3][row] = f2bf(v.w * sc);
    }
    __syncthreads();
    #pragma unroll
    for (int ii = 0; ii < 4; ++ii) {
        int fidx = t + ii * 256;
        int row = fidx >> 4, c4 = fidx & 15;
        u16x4 v;
        v[0] = T[row][c4 * 4 + 0]; v[1] = T[row][c4 * 4 + 1];
        v[2] = T[row][c4 * 4 + 2]; v[3] = T[row][c4 * 4 + 3];
        *reinterpret_cast<u16x4*>(O + (size_t)(n0 + row) * DM + k0 + c4 * 4) = v;
    }
}

// ---------------- projection GEMM v2: BM=64 x BN=256 (A fp32 cvt redundancy 8x -> 4x)
// fp32 A [8192,1024] x bf16 Wt [n][k] -> bf16 out. 4 waves, wave-tile 32x128.
__global__ __launch_bounds__(256) void proj_gemm(
    const float* __restrict__ A0, const float* __restrict__ A1, const float* __restrict__ A2,
    const u16* __restrict__ B0, const u16* __restrict__ B1, const u16* __restrict__ B2,
    u16* __restrict__ O0, u16* __restrict__ O1, u16* __restrict__ O2)
{
    const float* A; const u16* Bw; u16* Out;
    if (blockIdx.z == 0)      { A = A0; Bw = B0; Out = O0; }
    else if (blockIdx.z == 1) { A = A1; Bw = B1; Out = O1; }
    else                      { A = A2; Bw = B2; Out = O2; }

    __shared__ u16 As[64][40];      // padded; fp32->bf16 via cvt_pk
    __shared__ u16 Bs[256 * 32];    // linear; staged via global_load_lds (16 KB)
    const int t = threadIdx.x;
    const int m0 = blockIdx.x * 64;
    const int n0 = blockIdx.y * 256;
    const int w = t >> 6, l = t & 63;
    const int wr = (w >> 1) * 32, wc = (w & 1) * 128;
    const int lr = l & 15, lk = l >> 4;
    const int brow = w * 16 + (l >> 2);            // B-stage row within a 64-row group
    const int bcol = (l & 3) * 8;                  // B-stage k offset (u16)

    f32x4 acc[2][8] = {};
    for (int kt = 0; kt < DM; kt += 32) {
        #pragma unroll
        for (int inst = 0; inst < 4; ++inst) {
            const u16* src = Bw + (size_t)(n0 + inst * 64 + brow) * DM + kt + bcol;
            __builtin_amdgcn_global_load_lds(src, &Bs[inst * 2048 + w * 512], 16, 0, 0);
        }
        #pragma unroll
        for (int ii = 0; ii < 2; ++ii) {
            int fidx = t + ii * 256;
            int row = fidx >> 3, c4 = fidx & 7;
            const float4 v = *reinterpret_cast<const float4*>(A + (size_t)(m0 + row) * DM + kt + c4 * 4);
            uint2 o = { pk2bf(v.x, v.y), pk2bf(v.z, v.w) };
            *reinterpret_cast<uint2*>(&As[row][c4 * 4]) = o;
        }
        __syncthreads();
        bf16x8 af[2], bfr[8];
        #pragma unroll
        for (int mi = 0; mi < 2; ++mi) af[mi] = ld_bf8(&As[wr + mi * 16 + lr][lk * 8]);
        #pragma unroll
        for (int ni = 0; ni < 8; ++ni) bfr[ni] = ld_bf8(&Bs[(wc + ni * 16 + lr) * 32 + lk * 8]);
        #pragma unroll
        for (int mi = 0; mi < 2; ++mi)
            #pragma unroll
            for (int ni = 0; ni < 8; ++ni)
                acc[mi][ni] = __builtin_amdgcn_mfma_f32_16x16x32_bf16(af[mi], bfr[ni], acc[mi][ni], 0, 0, 0);
        __syncthreads();
    }
    #pragma unroll
    for (int mi = 0; mi < 2; ++mi)
        #pragma unroll
        for (int ni = 0; ni < 8; ++ni)
            #pragma unroll
            for (int i = 0; i < 4; ++i) {
                int r = m0 + wr + mi * 16 + lk * 4 + i;
                int c = n0 + wc + ni * 16 + lr;
                Out[(size_t)r * DM + c] = f2bf(acc[mi][ni][i]);
            }
}

// ---------------- output GEMM: bf16 ctx x bf16 WtF [n][k] -> fp32 out + residual
__global__ __launch_bounds__(256) void out_gemm(
    const u16* __restrict__ A, const u16* __restrict__ Bw,
    const float* __restrict__ resid, float* __restrict__ Out)
{
    __shared__ u16 As[128 * 32];
    __shared__ u16 Bs[128 * 32];
    const int t = threadIdx.x;
    const int m0 = blockIdx.x * 128;
    const int n0 = blockIdx.y * 128;
    const int w = t >> 6, l = t & 63;
    const int wr = (w >> 1) * 64, wc = (w & 1) * 64;
    const int lr = l & 15, lk = l >> 4;
    const int srow = w * 16 + (l >> 2);
    const int scol = (l & 3) * 8;

    f32x4 acc[4][4] = {};
    for (int kt = 0; kt < DM; kt += 32) {
        #pragma unroll
        for (int inst = 0; inst < 2; ++inst) {
            const u16* srcA = A  + (size_t)(m0 + inst * 64 + srow) * DM + kt + scol;
            const u16* srcB = Bw + (size_t)(n0 + inst * 64 + srow) * DM + kt + scol;
            __builtin_amdgcn_global_load_lds(srcA, &As[inst * 2048 + w * 512], 16, 0, 0);
            __builtin_amdgcn_global_load_lds(srcB, &Bs[inst * 2048 + w * 512], 16, 0, 0);
        }
        __syncthreads();
        bf16x8 af[4], bfr[4];
        #pragma unroll
        for (int mi = 0; mi < 4; ++mi) af[mi] = ld_bf8(&As[(wr + mi * 16 + lr) * 32 + lk * 8]);
        #pragma unroll
        for (int ni = 0; ni < 4; ++ni) bfr[ni] = ld_bf8(&Bs[(wc + ni * 16 + lr) * 32 + lk * 8]);
        #pragma unroll
        for (int mi = 0; mi < 4; ++mi)
            #pragma unroll
            for (int ni = 0; ni < 4; ++ni)
                acc[mi][ni] = __builtin_amdgcn_mfma_f32_16x16x32_bf16(af[mi], bfr[ni], acc[mi][ni], 0, 0, 0);
        __syncthreads();
    }
    #pragma unroll
    for (int mi = 0; mi < 4; ++mi)
        #pragma unroll
        for (int ni = 0; ni < 4; ++ni)
            #pragma unroll
            for (int i = 0; i < 4; ++i) {
                int r = m0 + wr + mi * 16 + lk * 4 + i;
                int c = n0 + wc + ni * 16 + lr;
                Out[(size_t)r * DM + c] = acc[mi][ni][i] + resid[(size_t)r * DM + c];
            }
}

// ---------------- V transpose + k-permute (PV A-fragment order), as v4
__global__ __launch_bounds__(256) void v_transpose(const u16* __restrict__ Vp, u16* __restrict__ Vt)
{
    __shared__ u16 T[64][72];
    const int t = threadIdx.x;
    const int s0 = blockIdx.x * 64;
    const int h = blockIdx.y, b = blockIdx.z;
    #pragma unroll
    for (int ii = 0; ii < 4; ++ii) {
        int fidx = t + ii * 256;
        int row = fidx >> 4, c4 = fidx & 15;
        u16x4 v = *reinterpret_cast<const u16x4*>(Vp + (size_t)(b * SEQ + s0 + row) * DM + h * 64 + c4 * 4);
        T[c4 * 4 + 0][row] = v[0];
        T[c4 * 4 + 1][row] = v[1];
        T[c4 * 4 + 2][row] = v[2];
        T[c4 * 4 + 3][row] = v[3];
    }
    __syncthreads();
    #pragma unroll
    for (int ii = 0; ii < 4; ++ii) {
        int fidx = t + ii * 256;
        int dv = fidx >> 4, s4i = fidx & 15;
        u16x4 v;
        v[0] = T[dv][s4i * 4 + 0]; v[1] = T[dv][s4i * 4 + 1];
        v[2] = T[dv][s4i * 4 + 2]; v[3] = T[dv][s4i * 4 + 3];
        const int blk32 = (s4i >> 3) * 32;
        const int g5 = s4i & 7;
        const int dst = blk32 + (g5 & 3) * 8 + (g5 >> 2) * 4;
        *reinterpret_cast<u16x4*>(Vt + ((size_t)((b * NH + h) * 64 + dv)) * SEQ + s0 + dst) = v;
    }
}

// ---------------- mask bit-pack: mask bytes (0/1) -> 1 bit per col
__global__ __launch_bounds__(256) void mask_pack(const unsigned char* __restrict__ mask,
                                                 uint32_t* __restrict__ mbits)
{
    size_t idx = (size_t)blockIdx.x * 256 + threadIdx.x;
    const uint32_t* m32 = reinterpret_cast<const uint32_t*>(mask + idx * 32);
    uint32_t out = 0;
    #pragma unroll
    for (int j = 0; j < 8; ++j) {
        uint32_t y = m32[j] & 0x01010101u;
        uint32_t nib = (y * 0x01020408u) >> 24;
        out |= nib << (j * 4);
    }
    mbits[idx] = out;
}

// ---------------- attention v9: v8 + setprio around pass-1 compute cluster.
// K reg-staged, V via global_load_lds, nt attn stores, store-free barriers,
// swapped QK^T, in-register P->PV. 1024 blocks x 512 threads.
__global__ __launch_bounds__(512) void attn_kernel(
    const u16* __restrict__ Qb, const u16* __restrict__ Kb, const u16* __restrict__ Vt,
    const u64* __restrict__ mbits64,
    float* __restrict__ attn_out, u16* __restrict__ ctx)
{
    __shared__ u16 Kbuf[2][4096];        // 2 x (64 k-rows x 64 d) bf16, swizzled, 16 KiB
    __shared__ u16 Vbuf[2][4096];        // 2 x (64 dv-rows x 64 s) bf16, swizzled, 16 KiB
    const int t = threadIdx.x;
    const int w = t >> 6, l = t & 63;
    const int lr = l & 15, lk = l >> 4;

    // XCD-aware remap: consecutive block ids round-robin XCDs; each XCD gets 8 (b,h) pairs
    const int wg = blockIdx.x;           // 0..1023
    const int xcd = wg & 7;
    const int ix  = wg >> 3;             // 0..127
    const int pair = xcd * 8 + (ix >> 4);
    const int qt = ix & 15;
    const int h = pair & 15;
    const int b = pair >> 4;

    const int q0 = qt * 128 + w * 16;
    const int q  = q0 + lr;              // this lane's q row

    // Q as MFMA B-operand: lane holds Q[q][d=lk*8..+7]
    const size_t rowQ = (size_t)(b * SEQ + q) * DM + h * 64 + lk * 8;
    const bf16x8 bq0 = ld_bf8(Qb + rowQ);
    const bf16x8 bq1 = ld_bf8(Qb + rowQ + 32);

    // staging geometry (shared by K and V tiles): row = w*8+(l>>3), swizzled 16B chunk
    const int st_row0 = w * 8 + (l >> 3);
    const int st_col  = ((l & 7) ^ (l >> 3)) * 8;   // u16 units within a 128-B row
    const u16* kgbase = Kb + (size_t)(b * SEQ) * DM + h * 64;
    const u16* vgbase = Vt + (size_t)((b * NH + h) * 64 + st_row0) * SEQ + st_col;
    u16* const myLds0 = &Kbuf[0][w * 512 + l * 8];
    u16* const myLds1 = &Kbuf[1][w * 512 + l * 8];

    #define LOADK(c) (*reinterpret_cast<const u16x8*>(kgbase + (size_t)((c) * 64 + st_row0) * DM + st_col))
    #define PUTK(buf) { *reinterpret_cast<u16x8*>((buf) ? myLds1 : myLds0) = kreg; }
    // V gll issued BEFORE LOADK; PUTK's implicit vmcnt wait on kreg (younger) covers it.
    #define STAGEV(c, buf) { __builtin_amdgcn_global_load_lds(vgbase + (c) * 64, &Vbuf[buf][w * 512], 16, 0, 0); }
    #define BAR() { asm volatile("s_waitcnt lgkmcnt(0)" ::: "memory"); __builtin_amdgcn_s_barrier(); }

    // per-lane mask row (u64 word c covers k = c*64..c*64+63)
    const u64* mrow64 = mbits64 + (size_t)(b * SEQ + q) * 32;

    const int swz = (lr & 7) << 4;
    // swapped: A = K rows (LDS), B = Q. C: row = k-local (lk*4+i), col = q (lr).
    #define QK_TILE(kb, tile16, s4out)                                                      \
        {   const char* base_ = (const char*)(kb) + ((tile16) + lr) * 128;                  \
            bf16x8 ak0_ = ld_bf8((const u16*)(base_ + ((lk * 16) ^ swz)));                  \
            bf16x8 ak1_ = ld_bf8((const u16*)(base_ + ((64 + lk * 16) ^ swz)));             \
            s4out = __builtin_amdgcn_mfma_f32_16x16x32_bf16(ak0_, bq0, (f32x4){}, 0, 0, 0); \
            s4out = __builtin_amdgcn_mfma_f32_16x16x32_bf16(ak1_, bq1, s4out, 0, 0, 0);     \
        }

    u16x8 kreg;

    // -------- pass 1: row sum of exp2(scores) (K only)
    f32x4 sumv = {};
    kreg = LOADK(0);
    PUTK(0);
    BAR();
    for (int c = 0; c < 32; ++c) {
        if (c + 1 < 32) kreg = LOADK(c + 1);           // issue-early: hides under compute
        const u16* kb = &Kbuf[c & 1][0];
        const u64 mw = mrow64[c];
        const bool anym = __any(mw != 0);
        __builtin_amdgcn_s_setprio(1);
        #pragma unroll
        for (int tl = 0; tl < 4; ++tl) {
            f32x4 s4;
            QK_TILE(kb, tl * 16, s4);
            if (anym) {
                #pragma unroll
                for (int i = 0; i < 4; ++i)
                    if ((mw >> (tl * 16 + lk * 4 + i)) & 1ull) s4[i] = NEGINF;
            }
            #pragma unroll
            for (int i = 0; i < 4; ++i) sumv[i] += ex2(s4[i]);
        }
        __builtin_amdgcn_s_setprio(0);
        if (c + 1 < 32) PUTK((c & 1) ^ 1);             // write-late: waits only kreg
        BAR();
    }
    float sum = sumv[0] + sumv[1] + sumv[2] + sumv[3];
    sum += __shfl_xor(sum, 16);
    sum += __shfl_xor(sum, 32);
    const float invl = 1.0f / sum;

    // -------- pass 2: normalized attn (nt dwordx4) + PV from LDS-shared V
    f32x4 cacc[4] = {};
    const size_t attnBase = (size_t)(b * NH + h) * SEQ * SEQ + (size_t)q * SEQ;
    STAGEV(0, 0);
    kreg = LOADK(0);
    PUTK(0);                                           // vmcnt wait covers STAGEV(0) too
    BAR();
    for (int c = 0; c < 32; ++c) {
        if (c + 1 < 32) {
            STAGEV(c + 1, (c & 1) ^ 1);                // issue V gll first
            kreg = LOADK(c + 1);                       // then K reg load
        }
        const u16* kb = &Kbuf[c & 1][0];
        const char* vb = (const char*)&Vbuf[c & 1][0];
        const u64 mw = mrow64[c];
        const bool anym = __any(mw != 0);
        #pragma unroll
        for (int hs = 0; hs < 2; ++hs) {
            float pn[8];
            #pragma unroll
            for (int tt2 = 0; tt2 < 2; ++tt2) {
                const int tl = hs * 2 + tt2;
                f32x4 s4;
                QK_TILE(kb, tl * 16, s4);
                if (anym) {
                    #pragma unroll
                    for (int i = 0; i < 4; ++i)
                        if ((mw >> (tl * 16 + lk * 4 + i)) & 1ull) s4[i] = NEGINF;
                }
                #pragma unroll
                for (int i = 0; i < 4; ++i) pn[tt2 * 4 + i] = ex2(s4[i]) * invl;
                f32x4 st = { pn[tt2 * 4 + 0], pn[tt2 * 4 + 1], pn[tt2 * 4 + 2], pn[tt2 * 4 + 3] };
                __builtin_nontemporal_store(st,
                    reinterpret_cast<f32x4*>(attn_out + attnBase + c * 64 + tl * 16 + lk * 4));
            }
            // PV A-fragment straight from registers (Vt is k-permuted to match);
            // B-fragment from swizzled LDS V tile (same pattern as K reads).
            uint4 aw = { pk2bf(pn[0], pn[1]), pk2bf(pn[2], pn[3]),
                         pk2bf(pn[4], pn[5]), pk2bf(pn[6], pn[7]) };
            bf16x8 pa = __builtin_bit_cast(bf16x8, aw);
            __builtin_amdgcn_s_setprio(1);
            #pragma unroll
            for (int ni = 0; ni < 4; ++ni) {
                const char* bvb = vb + (ni * 16 + lr) * 128;
                bf16x8 bv = ld_bf8((const u16*)(bvb + ((hs * 64 + lk * 16) ^ swz)));
                cacc[ni] = __builtin_amdgcn_mfma_f32_16x16x32_bf16(pa, bv, cacc[ni], 0, 0, 0);
            }
            __builtin_amdgcn_s_setprio(0);
        }
        if (c + 1 < 32) PUTK((c & 1) ^ 1);
        BAR();
    }
    // C of PV: row = q-local (lk*4+i), col = dv (lr); P was pre-normalized
    #pragma unroll
    for (int ni = 0; ni < 4; ++ni)
        #pragma unroll
        for (int i = 0; i < 4; ++i)
            ctx[(size_t)(b * SEQ + q0 + lk * 4 + i) * DM + h * 64 + ni * 16 + lr] = f2bf(cacc[ni][i]);
    #undef LOADK
    #undef PUTK
    #undef STAGEV
    #undef BAR
    #undef QK_TILE
}

// ---------------- in-place LayerNorm over d_out[0 : 8192*1024]
__global__ __launch_bounds__(256) void ln_kernel(
    float* __restrict__ io, const float* __restrict__ gamma, const float* __restrict__ beta)
{
    const int t = threadIdx.x;
    const size_t row = blockIdx.x;
    float4 x = *reinterpret_cast<const float4*>(io + row * DM + t * 4);
    float s = x.x + x.y + x.z + x.w;
    float ss = x.x * x.x + x.y * x.y + x.z * x.z + x.w * x.w;
    #pragma unroll
    for (int off = 1; off < 64; off <<= 1) {
        s += __shfl_xor(s, off);
        ss += __shfl_xor(ss, off);
    }
    __shared__ float rs_[4], rss[4];
    __shared__ float s_mu, s_rs;
    const int w = t >> 6, l = t & 63;
    if (l == 0) { rs_[w] = s; rss[w] = ss; }
    __syncthreads();
    if (t == 0) {
        float S = rs_[0] + rs_[1] + rs_[2] + rs_[3];
        float SS = rss[0] + rss[1] + rss[2] + rss[3];
        float mu = S / DM;
        float var = fmaxf(SS / DM - mu * mu, 0.f);
        s_mu = mu;
        s_rs = rsqrtf(var + 1e-5f);
    }
    __syncthreads();
    float mu = s_mu, r = s_rs;
    float4 g = *reinterpret_cast<const float4*>(gamma + t * 4);
    float4 bb = *reinterpret_cast<const float4*>(beta + t * 4);
    float4 y;
    y.x = (x.x - mu) * r * g.x + bb.x;
    y.y = (x.y - mu) * r * g.y + bb.y;
    y.z = (x.z - mu) * r * g.z + bb.z;
    y.w = (x.w - mu) * r * g.w + bb.w;
    *reinterpret_cast<float4*>(io + row * DM + t * 4) = y;
}

extern "C" void kernel_launch(void* const* d_in, const int* in_sizes, int n_in,
                              void* d_out, int out_size, void* d_ws, size_t ws_size,
                              hipStream_t stream) {
    const float* inQ = (const float*)d_in[0];
    const float* inK = (const float*)d_in[1];
    const float* inV = (const float*)d_in[2];
    const unsigned char* mask = (const unsigned char*)d_in[3];
    const float* WQ = (const float*)d_in[4];
    const float* WK = (const float*)d_in[5];
    const float* WV = (const float*)d_in[6];
    const float* Wfc = (const float*)d_in[7];
    const float* gamma = (const float*)d_in[8];
    const float* beta = (const float*)d_in[9];
    float* out = (float*)d_out;

    // workspace layout (84 MiB total, SZ = 16.78 MiB):
    //  [0,SZ)    Qb
    //  [SZ,2SZ)  Kb
    //  [2SZ,3SZ) WtQ|WtK|WtV|WtF (4 x 2 MiB) + mbits (2 MiB at +8 MiB)
    //  [3SZ,4SZ) Vt (k-permuted)
    //  [4SZ,5SZ) V-projection, later overwritten by ctx (V dead after v_transpose)
    char* ws = (char*)d_ws;
    const size_t SZ = (size_t)8192 * 1024 * sizeof(u16);
    u16* Qb  = (u16*)(ws);
    u16* Kb  = (u16*)(ws + SZ);
    u16* WtQ = (u16*)(ws + 2 * SZ);
    u16* WtK = WtQ + (size_t)1024 * 1024;
    u16* WtV = WtK + (size_t)1024 * 1024;
    u16* WtF = WtV + (size_t)1024 * 1024;
    uint32_t* mbits = (uint32_t*)(ws + 2 * SZ + ((size_t)8 << 20));
    u16* Vt  = (u16*)(ws + 3 * SZ);
    u16* Vp  = (u16*)(ws + 4 * SZ);   // V projection
    u16* ctx = (u16*)(ws + 4 * SZ);   // reused after v_transpose

    dim3 blk(256);
    conv_wt<<<dim3(16, 16, 4), blk, 0, stream>>>(WQ, WK, WV, Wfc, WtQ, WtK, WtV, WtF);
    mask_pack<<<dim3(2048), blk, 0, stream>>>(mask, mbits);
    proj_gemm<<<dim3(128, 4, 3), blk, 0, stream>>>(inQ, inK, inV, WtQ, WtK, WtV, Qb, Kb, Vp);
    v_transpose<<<dim3(32, 16, 4), blk, 0, stream>>>(Vp, Vt);
    attn_kernel<<<dim3(1024), dim3(512), 0, stream>>>(Qb, Kb, Vt, (const u64*)mbits,
                                                      out + 8388608, ctx);
    out_gemm<<<dim3(64, 8), blk, 0, stream>>>(ctx, WtF, inQ, out);
    ln_kernel<<<8192, blk, 0, stream>>>(out, gamma, beta);
}

// Round 10
// 462.671 us; speedup vs baseline: 1.0463x; 1.0463x over previous
//
#include <hip/hip_runtime.h>
#include <hip/hip_bf16.h>
#include <cstdint>

#define DM   1024
#define SEQ  2048
#define NB   4
#define NH   16
// 0.125 * log2(e): folded into W_Q at conversion so exp2(mfma result) is the softmax numerator
#define QSCALE 0.18033688011112042f
#define NEGINF __builtin_bit_cast(float, 0xFF800000u)

typedef __bf16 bf16x8 __attribute__((ext_vector_type(8)));
typedef float  f32x4  __attribute__((ext_vector_type(4)));
typedef unsigned short u16;
typedef u16 u16x4 __attribute__((ext_vector_type(4)));
typedef u16 u16x8 __attribute__((ext_vector_type(8)));
typedef unsigned long long u64;

__device__ __forceinline__ u16 f2bf(float f) {
    uint32_t u = __builtin_bit_cast(uint32_t, f);
    u = (u + 0x7FFFu + ((u >> 16) & 1u)) >> 16;
    return (u16)u;
}
// packed f32 pair -> bf16 pair (RNE), single VALU op
__device__ __forceinline__ uint32_t pk2bf(float lo, float hi) {
    uint32_t r;
    asm("v_cvt_pk_bf16_f32 %0, %1, %2" : "=v"(r) : "v"(lo), "v"(hi));
    return r;
}
__device__ __forceinline__ float ex2(float x) { return __builtin_amdgcn_exp2f(x); }
__device__ __forceinline__ bf16x8 ld_bf8(const u16* p) {
    return __builtin_bit_cast(bf16x8, *reinterpret_cast<const u16x8*>(p));
}

// ---------------- weight convert + transpose: W fp32 [k][n] -> Wt bf16 [n][k] (scaled)
__global__ __launch_bounds__(256) void conv_wt(
    const float* __restrict__ W0, const float* __restrict__ W1,
    const float* __restrict__ W2, const float* __restrict__ W3,
    u16* __restrict__ T0, u16* __restrict__ T1, u16* __restrict__ T2, u16* __restrict__ T3)
{
    const float* W; u16* O; float sc = 1.0f;
    if (blockIdx.z == 0)      { W = W0; O = T0; sc = QSCALE; }
    else if (blockIdx.z == 1) { W = W1; O = T1; }
    else if (blockIdx.z == 2) { W = W2; O = T2; }
    else                      { W = W3; O = T3; }
    __shared__ u16 T[64][72];
    const int t = threadIdx.x;
    const int k0 = blockIdx.x * 64, n0 = blockIdx.y * 64;
    #pragma unroll
    for (int ii = 0; ii < 4; ++ii) {
        int fidx = t + ii * 256;
        int row = fidx >> 4, c4 = fidx & 15;
        float4 v = *reinterpret_cast<const float4*>(W + (size_t)(k0 + row) * DM + n0 + c4 * 4);
        T[c4 * 4 + 0][row] = f2bf(v.x * sc);
        T[c4 * 4 + 1][row] = f2bf(v.y * sc);
        T[c4 * 4 + 2][row] = f2bf(v.z * sc);
        T[c4 * 4 + 3][row] = f2bf(v.w * sc);
    }
    __syncthreads();
    #pragma unroll
    for (int ii = 0; ii < 4; ++ii) {
        int fidx = t + ii * 256;
        int row = fidx >> 4, c4 = fidx & 15;
        u16x4 v;
        v[0] = T[row][c4 * 4 + 0]; v[1] = T[row][c4 * 4 + 1];
        v[2] = T[row][c4 * 4 + 2]; v[3] = T[row][c4 * 4 + 3];
        *reinterpret_cast<u16x4*>(O + (size_t)(n0 + row) * DM + k0 + c4 * 4) = v;
    }
}

// ---------------- projection GEMM (r8 config): fp32 A x bf16 Wt [n][k] -> bf16 out, 128x128
__global__ __launch_bounds__(256) void proj_gemm(
    const float* __restrict__ A0, const float* __restrict__ A1, const float* __restrict__ A2,
    const u16* __restrict__ B0, const u16* __restrict__ B1, const u16* __restrict__ B2,
    u16* __restrict__ O0, u16* __restrict__ O1, u16* __restrict__ O2)
{
    const float* A; const u16* Bw; u16* Out;
    if (blockIdx.z == 0)      { A = A0; Bw = B0; Out = O0; }
    else if (blockIdx.z == 1) { A = A1; Bw = B1; Out = O1; }
    else                      { A = A2; Bw = B2; Out = O2; }

    __shared__ u16 As[128][40];
    __shared__ u16 Bs[128 * 32];
    const int t = threadIdx.x;
    const int m0 = blockIdx.x * 128;
    const int n0 = blockIdx.y * 128;
    const int w = t >> 6, l = t & 63;
    const int wr = (w >> 1) * 64, wc = (w & 1) * 64;
    const int lr = l & 15, lk = l >> 4;
    const int brow = w * 16 + (l >> 2);
    const int bcol = (l & 3) * 8;

    f32x4 acc[4][4] = {};
    for (int kt = 0; kt < DM; kt += 32) {
        #pragma unroll
        for (int inst = 0; inst < 2; ++inst) {
            const u16* src = Bw + (size_t)(n0 + inst * 64 + brow) * DM + kt + bcol;
            __builtin_amdgcn_global_load_lds(src, &Bs[inst * 2048 + w * 512], 16, 0, 0);
        }
        #pragma unroll
        for (int ii = 0; ii < 4; ++ii) {
            int fidx = t + ii * 256;
            int row = fidx >> 3, c4 = fidx & 7;
            const float4 v = *reinterpret_cast<const float4*>(A + (size_t)(m0 + row) * DM + kt + c4 * 4);
            uint2 o = { pk2bf(v.x, v.y), pk2bf(v.z, v.w) };
            *reinterpret_cast<uint2*>(&As[row][c4 * 4]) = o;
        }
        __syncthreads();
        bf16x8 af[4], bfr[4];
        #pragma unroll
        for (int mi = 0; mi < 4; ++mi) af[mi] = ld_bf8(&As[wr + mi * 16 + lr][lk * 8]);
        #pragma unroll
        for (int ni = 0; ni < 4; ++ni) bfr[ni] = ld_bf8(&Bs[(wc + ni * 16 + lr) * 32 + lk * 8]);
        #pragma unroll
        for (int mi = 0; mi < 4; ++mi)
            #pragma unroll
            for (int ni = 0; ni < 4; ++ni)
                acc[mi][ni] = __builtin_amdgcn_mfma_f32_16x16x32_bf16(af[mi], bfr[ni], acc[mi][ni], 0, 0, 0);
        __syncthreads();
    }
    #pragma unroll
    for (int mi = 0; mi < 4; ++mi)
        #pragma unroll
        for (int ni = 0; ni < 4; ++ni)
            #pragma unroll
            for (int i = 0; i < 4; ++i) {
                int r = m0 + wr + mi * 16 + lk * 4 + i;
                int c = n0 + wc + ni * 16 + lr;
                Out[(size_t)r * DM + c] = f2bf(acc[mi][ni][i]);
            }
}

// ---------------- output GEMM: bf16 ctx x bf16 WtF [n][k] -> fp32 out + residual
__global__ __launch_bounds__(256) void out_gemm(
    const u16* __restrict__ A, const u16* __restrict__ Bw,
    const float* __restrict__ resid, float* __restrict__ Out)
{
    __shared__ u16 As[128 * 32];
    __shared__ u16 Bs[128 * 32];
    const int t = threadIdx.x;
    const int m0 = blockIdx.x * 128;
    const int n0 = blockIdx.y * 128;
    const int w = t >> 6, l = t & 63;
    const int wr = (w >> 1) * 64, wc = (w & 1) * 64;
    const int lr = l & 15, lk = l >> 4;
    const int srow = w * 16 + (l >> 2);
    const int scol = (l & 3) * 8;

    f32x4 acc[4][4] = {};
    for (int kt = 0; kt < DM; kt += 32) {
        #pragma unroll
        for (int inst = 0; inst < 2; ++inst) {
            const u16* srcA = A  + (size_t)(m0 + inst * 64 + srow) * DM + kt + scol;
            const u16* srcB = Bw + (size_t)(n0 + inst * 64 + srow) * DM + kt + scol;
            __builtin_amdgcn_global_load_lds(srcA, &As[inst * 2048 + w * 512], 16, 0, 0);
            __builtin_amdgcn_global_load_lds(srcB, &Bs[inst * 2048 + w * 512], 16, 0, 0);
        }
        __syncthreads();
        bf16x8 af[4], bfr[4];
        #pragma unroll
        for (int mi = 0; mi < 4; ++mi) af[mi] = ld_bf8(&As[(wr + mi * 16 + lr) * 32 + lk * 8]);
        #pragma unroll
        for (int ni = 0; ni < 4; ++ni) bfr[ni] = ld_bf8(&Bs[(wc + ni * 16 + lr) * 32 + lk * 8]);
        #pragma unroll
        for (int mi = 0; mi < 4; ++mi)
            #pragma unroll
            for (int ni = 0; ni < 4; ++ni)
                acc[mi][ni] = __builtin_amdgcn_mfma_f32_16x16x32_bf16(af[mi], bfr[ni], acc[mi][ni], 0, 0, 0);
        __syncthreads();
    }
    #pragma unroll
    for (int mi = 0; mi < 4; ++mi)
        #pragma unroll
        for (int ni = 0; ni < 4; ++ni)
            #pragma unroll
            for (int i = 0; i < 4; ++i) {
                int r = m0 + wr + mi * 16 + lk * 4 + i;
                int c = n0 + wc + ni * 16 + lr;
                Out[(size_t)r * DM + c] = acc[mi][ni][i] + resid[(size_t)r * DM + c];
            }
}

// ---------------- V transpose + k-permute (PV A-fragment order), as v4
__global__ __launch_bounds__(256) void v_transpose(const u16* __restrict__ Vp, u16* __restrict__ Vt)
{
    __shared__ u16 T[64][72];
    const int t = threadIdx.x;
    const int s0 = blockIdx.x * 64;
    const int h = blockIdx.y, b = blockIdx.z;
    #pragma unroll
    for (int ii = 0; ii < 4; ++ii) {
        int fidx = t + ii * 256;
        int row = fidx >> 4, c4 = fidx & 15;
        u16x4 v = *reinterpret_cast<const u16x4*>(Vp + (size_t)(b * SEQ + s0 + row) * DM + h * 64 + c4 * 4);
        T[c4 * 4 + 0][row] = v[0];
        T[c4 * 4 + 1][row] = v[1];
        T[c4 * 4 + 2][row] = v[2];
        T[c4 * 4 + 3][row] = v[3];
    }
    __syncthreads();
    #pragma unroll
    for (int ii = 0; ii < 4; ++ii) {
        int fidx = t + ii * 256;
        int dv = fidx >> 4, s4i = fidx & 15;
        u16x4 v;
        v[0] = T[dv][s4i * 4 + 0]; v[1] = T[dv][s4i * 4 + 1];
        v[2] = T[dv][s4i * 4 + 2]; v[3] = T[dv][s4i * 4 + 3];
        const int blk32 = (s4i >> 3) * 32;
        const int g5 = s4i & 7;
        const int dst = blk32 + (g5 & 3) * 8 + (g5 >> 2) * 4;
        *reinterpret_cast<u16x4*>(Vt + ((size_t)((b * NH + h) * 64 + dv)) * SEQ + s0 + dst) = v;
    }
}

// ---------------- mask bit-pack: mask bytes (0/1) -> 1 bit per col
__global__ __launch_bounds__(256) void mask_pack(const unsigned char* __restrict__ mask,
                                                 uint32_t* __restrict__ mbits)
{
    size_t idx = (size_t)blockIdx.x * 256 + threadIdx.x;
    const uint32_t* m32 = reinterpret_cast<const uint32_t*>(mask + idx * 32);
    uint32_t out = 0;
    #pragma unroll
    for (int j = 0; j < 8; ++j) {
        uint32_t y = m32[j] & 0x01010101u;
        uint32_t nib = (y * 0x01020408u) >> 24;
        out |= nib << (j * 4);
    }
    mbits[idx] = out;
}

// ---------------- attention v10: pass-1 runs 2 chunks per barrier on a 4-buffer K ring
// (halves pass-1 barrier count); pass 2 unchanged from v8 (write-bound), aliasing
// Kbuf[2..3] as the V double-buffer. 1024 blocks x 512 threads.
__global__ __launch_bounds__(512) void attn_kernel(
    const u16* __restrict__ Qb, const u16* __restrict__ Kb, const u16* __restrict__ Vt,
    const u64* __restrict__ mbits64,
    float* __restrict__ attn_out, u16* __restrict__ ctx)
{
    __shared__ u16 Kbuf[4][4096];        // pass1: 4-deep K ring; pass2: [0,1]=K dbuf, [2,3]=V dbuf
    const int t = threadIdx.x;
    const int w = t >> 6, l = t & 63;
    const int lr = l & 15, lk = l >> 4;

    // XCD-aware remap: consecutive block ids round-robin XCDs; each XCD gets 8 (b,h) pairs
    const int wg = blockIdx.x;           // 0..1023
    const int xcd = wg & 7;
    const int ix  = wg >> 3;             // 0..127
    const int pair = xcd * 8 + (ix >> 4);
    const int qt = ix & 15;
    const int h = pair & 15;
    const int b = pair >> 4;

    const int q0 = qt * 128 + w * 16;
    const int q  = q0 + lr;              // this lane's q row

    // Q as MFMA B-operand: lane holds Q[q][d=lk*8..+7]
    const size_t rowQ = (size_t)(b * SEQ + q) * DM + h * 64 + lk * 8;
    const bf16x8 bq0 = ld_bf8(Qb + rowQ);
    const bf16x8 bq1 = ld_bf8(Qb + rowQ + 32);

    // staging geometry (shared by K and V tiles): row = w*8+(l>>3), swizzled 16B chunk
    const int st_row0 = w * 8 + (l >> 3);
    const int st_col  = ((l & 7) ^ (l >> 3)) * 8;   // u16 units within a 128-B row
    const u16* kgbase = Kb + (size_t)(b * SEQ) * DM + h * 64;
    const u16* vgbase = Vt + (size_t)((b * NH + h) * 64 + st_row0) * SEQ + st_col;
    const int myoff = w * 512 + l * 8;

    #define LOADK(c) (*reinterpret_cast<const u16x8*>(kgbase + (size_t)((c) * 64 + st_row0) * DM + st_col))
    #define PUTK(bufidx, reg) { *reinterpret_cast<u16x8*>(&Kbuf[bufidx][myoff]) = (reg); }
    #define STAGEV(c, buf) { __builtin_amdgcn_global_load_lds(vgbase + (c) * 64, &Kbuf[2 + (buf)][w * 512], 16, 0, 0); }
    #define BAR() { asm volatile("s_waitcnt lgkmcnt(0)" ::: "memory"); __builtin_amdgcn_s_barrier(); }

    // per-lane mask row (u64 word c covers k = c*64..c*64+63)
    const u64* mrow64 = mbits64 + (size_t)(b * SEQ + q) * 32;

    const int swz = (lr & 7) << 4;
    // swapped: A = K rows (LDS), B = Q. C: row = k-local (lk*4+i), col = q (lr).
    #define QK_TILE(kb, tile16, s4out)                                                      \
        {   const char* base_ = (const char*)(kb) + ((tile16) + lr) * 128;                  \
            bf16x8 ak0_ = ld_bf8((const u16*)(base_ + ((lk * 16) ^ swz)));                  \
            bf16x8 ak1_ = ld_bf8((const u16*)(base_ + ((64 + lk * 16) ^ swz)));             \
            s4out = __builtin_amdgcn_mfma_f32_16x16x32_bf16(ak0_, bq0, (f32x4){}, 0, 0, 0); \
            s4out = __builtin_amdgcn_mfma_f32_16x16x32_bf16(ak1_, bq1, s4out, 0, 0, 0);     \
        }

    // one-chunk pass-1 body: QK^T over 64 k-rows + masked exp2 accumulate
    #define P1_BODY(cidx, bufidx)                                                           \
        {   const u16* kb_ = &Kbuf[bufidx][0];                                              \
            const u64 mw_ = mrow64[cidx];                                                   \
            const bool anym_ = __any(mw_ != 0);                                             \
            _Pragma("unroll")                                                               \
            for (int tl = 0; tl < 4; ++tl) {                                                \
                f32x4 s4;                                                                   \
                QK_TILE(kb_, tl * 16, s4);                                                  \
                if (anym_) {                                                                \
                    _Pragma("unroll")                                                       \
                    for (int i = 0; i < 4; ++i)                                             \
                        if ((mw_ >> (tl * 16 + lk * 4 + i)) & 1ull) s4[i] = NEGINF;         \
                }                                                                           \
                _Pragma("unroll")                                                           \
                for (int i = 0; i < 4; ++i) sumv[i] += ex2(s4[i]);                          \
            }                                                                               \
        }

    u16x8 kreg0, kreg1;

    // -------- pass 1: row sum of exp2(scores); 2 chunks per barrier, 4-buffer ring
    f32x4 sumv = {};
    kreg0 = LOADK(0); kreg1 = LOADK(1);
    PUTK(0, kreg0); PUTK(1, kreg1);
    BAR();
    for (int cc = 0; cc < 16; ++cc) {
        const int c0 = cc * 2;
        const int b0 = c0 & 3, b1 = (c0 + 1) & 3;          // current pair of ring slots
        if (cc + 1 < 16) { kreg0 = LOADK(c0 + 2); kreg1 = LOADK(c0 + 3); }
        P1_BODY(c0, b0);
        P1_BODY(c0 + 1, b1);
        if (cc + 1 < 16) { PUTK((c0 + 2) & 3, kreg0); PUTK((c0 + 3) & 3, kreg1); }
        BAR();
    }
    float sum = sumv[0] + sumv[1] + sumv[2] + sumv[3];
    sum += __shfl_xor(sum, 16);
    sum += __shfl_xor(sum, 32);
    const float invl = 1.0f / sum;

    // -------- pass 2: normalized attn (nt dwordx4) + PV from LDS-shared V (unchanged v8)
    f32x4 cacc[4] = {};
    const size_t attnBase = (size_t)(b * NH + h) * SEQ * SEQ + (size_t)q * SEQ;
    STAGEV(0, 0);
    kreg0 = LOADK(0);
    PUTK(0, kreg0);                                    // vmcnt wait covers STAGEV(0) too
    BAR();
    for (int c = 0; c < 32; ++c) {
        if (c + 1 < 32) {
            STAGEV(c + 1, (c & 1) ^ 1);                // issue V gll first
            kreg0 = LOADK(c + 1);                      // then K reg load
        }
        const u16* kb = &Kbuf[c & 1][0];
        const char* vb = (const char*)&Kbuf[2 + (c & 1)][0];
        const u64 mw = mrow64[c];
        const bool anym = __any(mw != 0);
        #pragma unroll
        for (int hs = 0; hs < 2; ++hs) {
            float pn[8];
            #pragma unroll
            for (int tt2 = 0; tt2 < 2; ++tt2) {
                const int tl = hs * 2 + tt2;
                f32x4 s4;
                QK_TILE(kb, tl * 16, s4);
                if (anym) {
                    #pragma unroll
                    for (int i = 0; i < 4; ++i)
                        if ((mw >> (tl * 16 + lk * 4 + i)) & 1ull) s4[i] = NEGINF;
                }
                #pragma unroll
                for (int i = 0; i < 4; ++i) pn[tt2 * 4 + i] = ex2(s4[i]) * invl;
                f32x4 st = { pn[tt2 * 4 + 0], pn[tt2 * 4 + 1], pn[tt2 * 4 + 2], pn[tt2 * 4 + 3] };
                __builtin_nontemporal_store(st,
                    reinterpret_cast<f32x4*>(attn_out + attnBase + c * 64 + tl * 16 + lk * 4));
            }
            // PV A-fragment straight from registers (Vt is k-permuted to match);
            // B-fragment from swizzled LDS V tile (same pattern as K reads).
            uint4 aw = { pk2bf(pn[0], pn[1]), pk2bf(pn[2], pn[3]),
                         pk2bf(pn[4], pn[5]), pk2bf(pn[6], pn[7]) };
            bf16x8 pa = __builtin_bit_cast(bf16x8, aw);
            __builtin_amdgcn_s_setprio(1);
            #pragma unroll
            for (int ni = 0; ni < 4; ++ni) {
                const char* bvb = vb + (ni * 16 + lr) * 128;
                bf16x8 bv = ld_bf8((const u16*)(bvb + ((hs * 64 + lk * 16) ^ swz)));
                cacc[ni] = __builtin_amdgcn_mfma_f32_16x16x32_bf16(pa, bv, cacc[ni], 0, 0, 0);
            }
            __builtin_amdgcn_s_setprio(0);
        }
        if (c + 1 < 32) PUTK((c & 1) ^ 1, kreg0);
        BAR();
    }
    // C of PV: row = q-local (lk*4+i), col = dv (lr); P was pre-normalized
    #pragma unroll
    for (int ni = 0; ni < 4; ++ni)
        #pragma unroll
        for (int i = 0; i < 4; ++i)
            ctx[(size_t)(b * SEQ + q0 + lk * 4 + i) * DM + h * 64 + ni * 16 + lr] = f2bf(cacc[ni][i]);
    #undef LOADK
    #undef PUTK
    #undef STAGEV
    #undef BAR
    #undef QK_TILE
    #undef P1_BODY
}

// ---------------- in-place LayerNorm over d_out[0 : 8192*1024]
__global__ __launch_bounds__(256) void ln_kernel(
    float* __restrict__ io, const float* __restrict__ gamma, const float* __restrict__ beta)
{
    const int t = threadIdx.x;
    const size_t row = blockIdx.x;
    float4 x = *reinterpret_cast<const float4*>(io + row * DM + t * 4);
    float s = x.x + x.y + x.z + x.w;
    float ss = x.x * x.x + x.y * x.y + x.z * x.z + x.w * x.w;
    #pragma unroll
    for (int off = 1; off < 64; off <<= 1) {
        s += __shfl_xor(s, off);
        ss += __shfl_xor(ss, off);
    }
    __shared__ float rs_[4], rss[4];
    __shared__ float s_mu, s_rs;
    const int w = t >> 6, l = t & 63;
    if (l == 0) { rs_[w] = s; rss[w] = ss; }
    __syncthreads();
    if (t == 0) {
        float S = rs_[0] + rs_[1] + rs_[2] + rs_[3];
        float SS = rss[0] + rss[1] + rss[2] + rss[3];
        float mu = S / DM;
        float var = fmaxf(SS / DM - mu * mu, 0.f);
        s_mu = mu;
        s_rs = rsqrtf(var + 1e-5f);
    }
    __syncthreads();
    float mu = s_mu, r = s_rs;
    float4 g = *reinterpret_cast<const float4*>(gamma + t * 4);
    float4 bb = *reinterpret_cast<const float4*>(beta + t * 4);
    float4 y;
    y.x = (x.x - mu) * r * g.x + bb.x;
    y.y = (x.y - mu) * r * g.y + bb.y;
    y.z = (x.z - mu) * r * g.z + bb.z;
    y.w = (x.w - mu) * r * g.w + bb.w;
    *reinterpret_cast<float4*>(io + row * DM + t * 4) = y;
}

extern "C" void kernel_launch(void* const* d_in, const int* in_sizes, int n_in,
                              void* d_out, int out_size, void* d_ws, size_t ws_size,
                              hipStream_t stream) {
    const float* inQ = (const float*)d_in[0];
    const float* inK = (const float*)d_in[1];
    const float* inV = (const float*)d_in[2];
    const unsigned char* mask = (const unsigned char*)d_in[3];
    const float* WQ = (const float*)d_in[4];
    const float* WK = (const float*)d_in[5];
    const float* WV = (const float*)d_in[6];
    const float* Wfc = (const float*)d_in[7];
    const float* gamma = (const float*)d_in[8];
    const float* beta = (const float*)d_in[9];
    float* out = (float*)d_out;

    // workspace layout (80 MiB total, SZ = 16 MiB):
    //  [0,SZ)    Qb
    //  [SZ,2SZ)  Kb
    //  [2SZ,3SZ) WtQ|WtK|WtV|WtF (4 x 2 MiB) + mbits (2 MiB at +8 MiB)
    //  [3SZ,4SZ) Vt (k-permuted)
    //  [4SZ,5SZ) V-projection, later overwritten by ctx (V dead after v_transpose)
    char* ws = (char*)d_ws;
    const size_t SZ = (size_t)8192 * 1024 * sizeof(u16);
    u16* Qb  = (u16*)(ws);
    u16* Kb  = (u16*)(ws + SZ);
    u16* WtQ = (u16*)(ws + 2 * SZ);
    u16* WtK = WtQ + (size_t)1024 * 1024;
    u16* WtV = WtK + (size_t)1024 * 1024;
    u16* WtF = WtV + (size_t)1024 * 1024;
    uint32_t* mbits = (uint32_t*)(ws + 2 * SZ + ((size_t)8 << 20));
    u16* Vt  = (u16*)(ws + 3 * SZ);
    u16* Vp  = (u16*)(ws + 4 * SZ);   // V projection
    u16* ctx = (u16*)(ws + 4 * SZ);   // reused after v_transpose

    dim3 blk(256);
    conv_wt<<<dim3(16, 16, 4), blk, 0, stream>>>(WQ, WK, WV, Wfc, WtQ, WtK, WtV, WtF);
    mask_pack<<<dim3(2048), blk, 0, stream>>>(mask, mbits);
    proj_gemm<<<dim3(64, 8, 3), blk, 0, stream>>>(inQ, inK, inV, WtQ, WtK, WtV, Qb, Kb, Vp);
    v_transpose<<<dim3(32, 16, 4), blk, 0, stream>>>(Vp, Vt);
    attn_kernel<<<dim3(1024), dim3(512), 0, stream>>>(Qb, Kb, Vt, (const u64*)mbits,
                                                      out + 8388608, ctx);
    out_gemm<<<dim3(64, 8), blk, 0, stream>>>(ctx, WtF, inQ, out);
    ln_kernel<<<8192, blk, 0, stream>>>(out, gamma, beta);
}